// Round 1
// 1363.303 us; speedup vs baseline: 2.0537x; 2.0537x over previous
//
#include <hip/hip_runtime.h>

typedef _Float16 half8 __attribute__((ext_vector_type(8)));
typedef _Float16 half4 __attribute__((ext_vector_type(4)));
typedef float f32x4 __attribute__((ext_vector_type(4)));

#define NSTEP 48
#define MT 16
#define LDX 264    // x row stride (halfs): 132 words, %32=4 -> 8 lanes/bank on b128 reads (optimal)
#define LDH0 296   // h0 + ext(sn+zeros) row stride: 148 words, %32=20 -> optimal spread
#define LDH1 264

__device__ __forceinline__ float sigm(float x) { return 1.0f / (1.0f + __expf(-x)); }
__device__ __forceinline__ float tanh_f(float x) {
  float ax = fabsf(x);
  float e = __expf(-2.0f * ax);
  float t = (1.0f - e) / (1.0f + e);
  return copysignf(t, x);
}

// Fragment-order packed weights (coalesced: one 1KB contiguous block per (w,kt,c)):
//   W0p[w][kt(17)][c(4)][lane(64)=(q<<4|r)][j(8)] = W0[c*256 + w*16 + r][kt*32 + q*8 + j]
//     where W0 K-layout = [256 x-feat | 256 h0 | 3 shifted-notes | 29 zeros]
//   W1p[w][kt(16)][c][lane][j] = W1[c*256 + w*16 + r][kt*32 + q*8 + j], K = [256 h0new | 256 h1]
__global__ void prep_weights(const float* __restrict__ Wih0, const float* __restrict__ Whh0,
                             const float* __restrict__ bih0, const float* __restrict__ bhh0,
                             const float* __restrict__ Wih1, const float* __restrict__ Whh1,
                             const float* __restrict__ bih1, const float* __restrict__ bhh1,
                             _Float16* __restrict__ W0p, _Float16* __restrict__ W1p,
                             float* __restrict__ b0, float* __restrict__ b1) {
  int n = blockIdx.x;              // gate-row 0..1023
  int c = n >> 8, u = n & 255, w = u >> 4, r = u & 15;
  for (int k = threadIdx.x; k < 544; k += 256) {
    int kt = k >> 5, kk = k & 31, q = kk >> 3, j = kk & 7;
    float val;
    if (k < 256) val = Wih0[n * 259 + k];
    else if (k < 512) val = Whh0[n * 256 + (k - 256)];
    else if (k < 515) val = Wih0[n * 259 + 256 + (k - 512)];
    else val = 0.0f;
    W0p[((((w * 17 + kt) * 4 + c) * 64) + q * 16 + r) * 8 + j] = (_Float16)val;
  }
  for (int k = threadIdx.x; k < 512; k += 256) {
    int kt = k >> 5, kk = k & 31, q = kk >> 3, j = kk & 7;
    float val = (k < 256) ? Wih1[n * 256 + k] : Whh1[n * 256 + (k - 256)];
    W1p[((((w * 16 + kt) * 4 + c) * 64) + q * 16 + r) * 8 + j] = (_Float16)val;
  }
  if (threadIdx.x == 0) { b0[n] = bih0[n] + bhh0[n]; b1[n] = bih1[n] + bhh1[n]; }
}

// 16 waves per WG (4/SIMD). Wave w owns units [w*16, w*16+16) x all 4 gates.
// D tile per wave: 16 batch x 16 units; acc[c] = f32x4 over batch rows q*4+g.
__global__ __launch_bounds__(1024, 4)
void noteaxis_main(const float* __restrict__ nf, const float* __restrict__ cond,
                   const _Float16* __restrict__ W0p, const _Float16* __restrict__ W1p,
                   const float* __restrict__ b0g, const float* __restrict__ b1g,
                   const float* __restrict__ Wout, const float* __restrict__ bout,
                   float* __restrict__ out) {
  __shared__ __align__(16) _Float16 lds_x[MT][LDX];
  __shared__ __align__(16) _Float16 lds_h0[MT][LDH0];
  __shared__ __align__(16) _Float16 lds_h1[MT][LDH1];
  __shared__ float lds_part[16][MT][3];

  const int tid = threadIdx.x;
  const int w = tid >> 6;        // wave 0..15: unit slice
  const int lane = tid & 63;
  const int r = lane & 15;       // A row = batch row; B col = unit-within-slice; D col
  const int q = lane >> 4;       // k sub-chunk / D row group
  const int u = w * 16 + r;      // this lane's unit column
  const int row0 = blockIdx.x * MT;

  for (int i = tid; i < MT * LDH0; i += 1024) ((_Float16*)lds_h0)[i] = (_Float16)0.0f;
  for (int i = tid; i < MT * LDH1; i += 1024) ((_Float16*)lds_h1)[i] = (_Float16)0.0f;

  // per-thread constants (replace per-step LDS bias reads)
  float b0c[4], b1c[4];
#pragma unroll
  for (int c = 0; c < 4; ++c) { b0c[c] = b0g[c * 256 + u]; b1c[c] = b1g[c * 256 + u]; }
  const float wov0 = Wout[u], wov1 = Wout[256 + u], wov2 = Wout[512 + u];
  const float bo0 = bout[0], bo1 = bout[1], bo2 = bout[2];

  float c0s[4], c1s[4];
#pragma unroll
  for (int g = 0; g < 4; ++g) { c0s[g] = 0.0f; c1s[g] = 0.0f; }

  const _Float16* pW0 = W0p + (size_t)w * (17 * 4 * 512) + lane * 8;
  const _Float16* pW1 = W1p + (size_t)w * (16 * 4 * 512) + lane * 8;

  f32x4 acc[4];
  half8 Ba[4], Bc[4];   // static double set (no runtime buffer index -> no scratch)

  auto loadW = [&](half8* d, const _Float16* base, int ktc4) {
#pragma unroll
    for (int c = 0; c < 4; ++c) d[c] = *(const half8*)(base + (ktc4 + c) * 512);
  };
  auto mfma4 = [&](half8 a, const half8* B) {
#pragma unroll
    for (int c = 0; c < 4; ++c)
      acc[c] = __builtin_amdgcn_mfma_f32_16x16x32_f16(a, B[c], acc[c], 0, 0, 0);
  };

  __syncthreads();

#pragma unroll 1
  for (int n = 0; n < NSTEP; ++n) {
    // ---- stage x (fp32->fp16, coalesced: one row per wave) + shifted notes ----
    {
      const float4 xv = *(const float4*)(nf + ((size_t)(row0 + w) * NSTEP + n) * 256 + lane * 4);
      half4 hx = { (_Float16)xv.x, (_Float16)xv.y, (_Float16)xv.z, (_Float16)xv.w };
      *(half4*)&lds_x[w][lane * 4] = hx;
    }
    if (tid < MT) {
      float s0 = 0.f, s1 = 0.f, s2 = 0.f;
      if (n > 0) {
        const float* cp = cond + ((size_t)(row0 + tid) * NSTEP + (n - 1)) * 3;
        s0 = cp[0]; s1 = cp[1]; s2 = cp[2];
      }
      lds_h0[tid][256] = (_Float16)s0;
      lds_h0[tid][257] = (_Float16)s1;
      lds_h0[tid][258] = (_Float16)s2;
    }
    __syncthreads();  // B0: x/sn staged; h0(n-1),h1(n-1) present

    // ================= Layer 0 =================
#pragma unroll
    for (int c = 0; c < 4; ++c) { f32x4 bz = {b0c[c], b0c[c], b0c[c], b0c[c]}; acc[c] = bz; }

#pragma unroll 2
    for (int kt = 0; kt < 8; kt += 2) {          // x part (kt 0..7)
      loadW(Ba, pW0, kt * 4);
      loadW(Bc, pW0, kt * 4 + 4);
      mfma4(*(const half8*)&lds_x[r][kt * 32 + q * 8], Ba);
      mfma4(*(const half8*)&lds_x[r][kt * 32 + 32 + q * 8], Bc);
    }
#pragma unroll 2
    for (int kt = 0; kt < 8; kt += 2) {          // h0 part (weight kt 8..15)
      loadW(Ba, pW0, 32 + kt * 4);
      loadW(Bc, pW0, 32 + kt * 4 + 4);
      mfma4(*(const half8*)&lds_h0[r][kt * 32 + q * 8], Ba);
      mfma4(*(const half8*)&lds_h0[r][kt * 32 + 32 + q * 8], Bc);
    }
    loadW(Ba, pW0, 64);                          // ext part: [sn | zeros] (weight kt 16)
    mfma4(*(const half8*)&lds_h0[r][256 + q * 8], Ba);

    __syncthreads();  // B1: all waves done reading lds_h0(n-1)/lds_x

    // ---- cell 0 ----
#pragma unroll
    for (int g = 0; g < 4; ++g) {
      float i_ = acc[0][g], f_ = acc[1][g], g_ = acc[2][g], o_ = acc[3][g];
      float cc = sigm(f_) * c0s[g] + sigm(i_) * tanh_f(g_);
      c0s[g] = cc;
      lds_h0[q * 4 + g][u] = (_Float16)(sigm(o_) * tanh_f(cc));
    }
    __syncthreads();  // B2: h0(n) visible

    // ================= Layer 1 =================
#pragma unroll
    for (int c = 0; c < 4; ++c) { f32x4 bz = {b1c[c], b1c[c], b1c[c], b1c[c]}; acc[c] = bz; }

#pragma unroll 2
    for (int kt = 0; kt < 8; kt += 2) {          // h0new part
      loadW(Ba, pW1, kt * 4);
      loadW(Bc, pW1, kt * 4 + 4);
      mfma4(*(const half8*)&lds_h0[r][kt * 32 + q * 8], Ba);
      mfma4(*(const half8*)&lds_h0[r][kt * 32 + 32 + q * 8], Bc);
    }
#pragma unroll 2
    for (int kt = 0; kt < 8; kt += 2) {          // h1 part (weight kt 8..15)
      loadW(Ba, pW1, 32 + kt * 4);
      loadW(Bc, pW1, 32 + kt * 4 + 4);
      mfma4(*(const half8*)&lds_h1[r][kt * 32 + q * 8], Ba);
      mfma4(*(const half8*)&lds_h1[r][kt * 32 + 32 + q * 8], Bc);
    }

    __syncthreads();  // B3: all waves done reading lds_h0(n)/lds_h1(n-1)

    // ---- cell 1 + output-projection partials ----
    float part[4][3];
#pragma unroll
    for (int g = 0; g < 4; ++g) {
      float i_ = acc[0][g], f_ = acc[1][g], g_ = acc[2][g], o_ = acc[3][g];
      float cc = sigm(f_) * c1s[g] + sigm(i_) * tanh_f(g_);
      c1s[g] = cc;
      float hh = sigm(o_) * tanh_f(cc);
      lds_h1[q * 4 + g][u] = (_Float16)hh;
      part[g][0] = hh * wov0;
      part[g][1] = hh * wov1;
      part[g][2] = hh * wov2;
    }
#pragma unroll
    for (int g = 0; g < 4; ++g)
#pragma unroll
      for (int ch = 0; ch < 3; ++ch) {
        float p = part[g][ch];
        p += __shfl_xor(p, 1);
        p += __shfl_xor(p, 2);
        p += __shfl_xor(p, 4);
        p += __shfl_xor(p, 8);
        part[g][ch] = p;
      }
    if (r == 0) {
#pragma unroll
      for (int g = 0; g < 4; ++g) {
        int m = q * 4 + g;
        lds_part[w][m][0] = part[g][0];
        lds_part[w][m][1] = part[g][1];
        lds_part[w][m][2] = part[g][2];
      }
    }
    __syncthreads();  // B4

    if (tid < MT * 3) {
      int m = tid / 3, ch = tid - m * 3;
      float s = (ch == 0 ? bo0 : (ch == 1 ? bo1 : bo2));
#pragma unroll
      for (int ww = 0; ww < 16; ++ww) s += lds_part[ww][m][ch];
      if (ch < 2) s = 1.0f / (1.0f + __expf(-s));
      out[((size_t)(row0 + m) * NSTEP + n) * 3 + ch] = s;
    }
  }
}

extern "C" void kernel_launch(void* const* d_in, const int* in_sizes, int n_in,
                              void* d_out, int out_size, void* d_ws, size_t ws_size,
                              hipStream_t stream) {
  const float* nf   = (const float*)d_in[0];
  const float* cond = (const float*)d_in[1];
  const float* Wih0 = (const float*)d_in[2];
  const float* Whh0 = (const float*)d_in[3];
  const float* bih0 = (const float*)d_in[4];
  const float* bhh0 = (const float*)d_in[5];
  const float* Wih1 = (const float*)d_in[6];
  const float* Whh1 = (const float*)d_in[7];
  const float* bih1 = (const float*)d_in[8];
  const float* bhh1 = (const float*)d_in[9];
  const float* Wout = (const float*)d_in[10];
  const float* bout = (const float*)d_in[11];
  float* out = (float*)d_out;

  _Float16* W0p = (_Float16*)d_ws;                 // 16*17*4*512 = 557056 halfs
  _Float16* W1p = W0p + 16 * 17 * 4 * 512;         // 16*16*4*512 = 524288 halfs
  float* b0 = (float*)(W1p + 16 * 16 * 4 * 512);   // 4 KB
  float* b1 = b0 + 1024;                           // 4 KB

  prep_weights<<<1024, 256, 0, stream>>>(Wih0, Whh0, bih0, bhh0, Wih1, Whh1, bih1, bhh1, W0p, W1p, b0, b1);
  noteaxis_main<<<256, 1024, 0, stream>>>(nf, cond, W0p, W1p, b0, b1, Wout, bout, out);
}